// Round 1
// baseline (44.883 us; speedup 1.0000x reference)
//
#include <hip/hip_runtime.h>

// PLE encoder: samples (B=8, C=64, L=2048) f32, bin_edges (C, 65) f32 sorted.
// out (B, C*64, L) f32: out[b][c*64+j][l] = 1 if j<bin, (x-left)/w if j==bin, 0 if j>bin
// where bin = #{inner edges <= x}, inner = edges[c][1..63].
//
// Memory-bound: 256 MB output write dominates. Each thread handles 4
// consecutive l for one (b,c) -> 64 float4 coalesced stores per thread.

#define PLE_B 8
#define PLE_C 64
#define PLE_L 2048
#define PLE_NBINS 64

__global__ __launch_bounds__(256) void ple_kernel(const float* __restrict__ samples,
                                                  const float* __restrict__ edges,
                                                  float* __restrict__ out) {
    __shared__ float se[PLE_NBINS + 1];

    const int bid  = blockIdx.x;
    const int tile = bid & 1;        // 2 tiles of 1024 l-values per (b,c)
    const int bc   = bid >> 1;
    const int c    = bc & (PLE_C - 1);
    const int b    = bc >> 6;        // / PLE_C
    const int tid  = threadIdx.x;

    if (tid < PLE_NBINS + 1) se[tid] = edges[c * (PLE_NBINS + 1) + tid];
    __syncthreads();

    const int l0 = tile * 1024 + tid * 4;
    const float4 x = *reinterpret_cast<const float4*>(
        samples + ((size_t)b * PLE_C + c) * PLE_L + l0);

    // searchsorted(inner, x, side='right') == count(inner <= x), inner = se[1..63]
    int bin0 = 0, bin1 = 0, bin2 = 0, bin3 = 0;
#pragma unroll
    for (int i = 1; i < PLE_NBINS; ++i) {
        const float e = se[i];           // wave-uniform LDS broadcast
        bin0 += (x.x >= e);
        bin1 += (x.y >= e);
        bin2 += (x.z >= e);
        bin3 += (x.w >= e);
    }

    const float bv0 = (x.x - se[bin0]) / (se[bin0 + 1] - se[bin0]);
    const float bv1 = (x.y - se[bin1]) / (se[bin1 + 1] - se[bin1]);
    const float bv2 = (x.z - se[bin2]) / (se[bin2 + 1] - se[bin2]);
    const float bv3 = (x.w - se[bin3]) / (se[bin3 + 1] - se[bin3]);

    float* outp = out + (((size_t)b * PLE_C + c) * PLE_NBINS) * PLE_L + l0;
#pragma unroll
    for (int j = 0; j < PLE_NBINS; ++j) {
        float4 v;
        v.x = (j < bin0) ? 1.0f : ((j == bin0) ? bv0 : 0.0f);
        v.y = (j < bin1) ? 1.0f : ((j == bin1) ? bv1 : 0.0f);
        v.z = (j < bin2) ? 1.0f : ((j == bin2) ? bv2 : 0.0f);
        v.w = (j < bin3) ? 1.0f : ((j == bin3) ? bv3 : 0.0f);
        *reinterpret_cast<float4*>(outp + (size_t)j * PLE_L) = v;
    }
}

extern "C" void kernel_launch(void* const* d_in, const int* in_sizes, int n_in,
                              void* d_out, int out_size, void* d_ws, size_t ws_size,
                              hipStream_t stream) {
    const float* samples = (const float*)d_in[0];
    const float* edges   = (const float*)d_in[1];
    float* out           = (float*)d_out;

    // grid: (B*C) pairs x 2 tiles; block handles 256*4 = 1024 l-values
    const int grid = PLE_B * PLE_C * 2;
    ple_kernel<<<grid, 256, 0, stream>>>(samples, edges, out);
}